// Round 1
// baseline (445.466 us; speedup 1.0000x reference)
//
#include <hip/hip_runtime.h>
#include <math.h>

#define NDIM 16
#define NHEADS 4
#define NDH 4
#define NMLP 4
#define NL 4
#define NOUT 16
#define NS 512
#define LEPS 1e-5f

// One block per batch element; one thread per sequence row.
// x-row lives in registers for the whole kernel; K/V in LDS per layer.
__global__ __launch_bounds__(NS)
void vit_fused(const float* __restrict__ gx,
               const float* __restrict__ g_ln1g, const float* __restrict__ g_ln1b,
               const float* __restrict__ g_inw,  const float* __restrict__ g_inb,
               const float* __restrict__ g_outw, const float* __restrict__ g_outb,
               const float* __restrict__ g_ln2g, const float* __restrict__ g_ln2b,
               const float* __restrict__ g_w1,   const float* __restrict__ g_b1,
               const float* __restrict__ g_w2,   const float* __restrict__ g_b2,
               const float* __restrict__ g_hg,   const float* __restrict__ g_hb,
               const float* __restrict__ g_hw,   const float* __restrict__ g_hbias,
               float* __restrict__ gout)
{
    __shared__ __align__(16) float sK[NS][NDIM];          // 32 KB
    __shared__ __align__(16) float sV[NS][NDIM];          // 32 KB
    __shared__ __align__(16) float sWiw[NL*48*NDIM];      // 12 KB
    __shared__ float sWib[NL*48];
    __shared__ __align__(16) float sWow[NL*NDIM*NDIM];    // 4 KB
    __shared__ float sWob[NL*NDIM];
    __shared__ float sLn1g[NL*NDIM], sLn1b[NL*NDIM], sLn2g[NL*NDIM], sLn2b[NL*NDIM];
    __shared__ __align__(16) float sW1[NL*NMLP*NDIM];
    __shared__ float sB1[NL*NMLP];
    __shared__ __align__(16) float sW2[NL*NDIM*NMLP];
    __shared__ float sB2[NL*NDIM];
    __shared__ float sHg[NDIM], sHb[NDIM];
    __shared__ __align__(16) float sHw[NOUT*NDIM];
    __shared__ float sHbias[NOUT];

    const int t = threadIdx.x;
    const int b = blockIdx.x;

    // ---- stage all weights to LDS once ----
    for (int i = t; i < NL*48*NDIM; i += NS) sWiw[i] = g_inw[i];
    for (int i = t; i < NL*48;       i += NS) sWib[i] = g_inb[i];
    for (int i = t; i < NL*NDIM*NDIM; i += NS) sWow[i] = g_outw[i];
    if (t < NL*NDIM) {
        sWob[t]  = g_outb[t];
        sLn1g[t] = g_ln1g[t];  sLn1b[t] = g_ln1b[t];
        sLn2g[t] = g_ln2g[t];  sLn2b[t] = g_ln2b[t];
        sB2[t]   = g_b2[t];
    }
    for (int i = t; i < NL*NMLP*NDIM; i += NS) { sW1[i] = g_w1[i]; sW2[i] = g_w2[i]; }
    if (t < NL*NMLP) sB1[t] = g_b1[t];
    if (t < NDIM)  { sHg[t] = g_hg[t]; sHb[t] = g_hb[t]; }
    if (t < NOUT)    sHbias[t] = g_hbias[t];
    for (int i = t; i < NOUT*NDIM; i += NS) sHw[i] = g_hw[i];

    // ---- load my x row (stays in registers across all layers) ----
    float xr[NDIM];
    {
        const float4* xg4 = (const float4*)(gx + ((size_t)b*NS + t)*NDIM);
        float4 a = xg4[0], b4 = xg4[1], c4 = xg4[2], d4 = xg4[3];
        xr[0]=a.x;  xr[1]=a.y;  xr[2]=a.z;  xr[3]=a.w;
        xr[4]=b4.x; xr[5]=b4.y; xr[6]=b4.z; xr[7]=b4.w;
        xr[8]=c4.x; xr[9]=c4.y; xr[10]=c4.z; xr[11]=c4.w;
        xr[12]=d4.x; xr[13]=d4.y; xr[14]=d4.z; xr[15]=d4.w;
    }

    __syncthreads();   // weights staged

    for (int li = 0; li < NL; ++li) {
        // ---- LN1 (per-row, registers) ----
        float mu = 0.f;
        #pragma unroll
        for (int c = 0; c < NDIM; ++c) mu += xr[c];
        mu *= (1.f/NDIM);
        float var = 0.f;
        #pragma unroll
        for (int c = 0; c < NDIM; ++c) { float d = xr[c]-mu; var += d*d; }
        var *= (1.f/NDIM);
        float rs = rsqrtf(var + LEPS);
        float hn[NDIM];
        #pragma unroll
        for (int c = 0; c < NDIM; ++c)
            hn[c] = (xr[c]-mu)*rs*sLn1g[li*NDIM+c] + sLn1b[li*NDIM+c];

        const float* iw = &sWiw[li*48*NDIM];
        const float* ib = &sWib[li*48];

        // q rows (pre-scaled by 1/sqrt(DH) = 0.5)
        float q[NDIM];
        #pragma unroll
        for (int r = 0; r < NDIM; ++r) {
            float acc = ib[r];
            #pragma unroll
            for (int c = 0; c < NDIM; ++c) acc += hn[c]*iw[r*NDIM+c];
            q[r] = acc*0.5f;
        }

        __syncthreads();   // everyone finished reading previous layer's K/V

        // K and V rows -> LDS (vector stores)
        {
            __align__(16) float tmp[NDIM];
            #pragma unroll
            for (int r = 0; r < NDIM; ++r) {
                float acc = ib[16+r];
                #pragma unroll
                for (int c = 0; c < NDIM; ++c) acc += hn[c]*iw[(16+r)*NDIM+c];
                tmp[r] = acc;
            }
            *(float4*)&sK[t][0]  = *(float4*)&tmp[0];
            *(float4*)&sK[t][4]  = *(float4*)&tmp[4];
            *(float4*)&sK[t][8]  = *(float4*)&tmp[8];
            *(float4*)&sK[t][12] = *(float4*)&tmp[12];
            #pragma unroll
            for (int r = 0; r < NDIM; ++r) {
                float acc = ib[32+r];
                #pragma unroll
                for (int c = 0; c < NDIM; ++c) acc += hn[c]*iw[(32+r)*NDIM+c];
                tmp[r] = acc;
            }
            *(float4*)&sV[t][0]  = *(float4*)&tmp[0];
            *(float4*)&sV[t][4]  = *(float4*)&tmp[4];
            *(float4*)&sV[t][8]  = *(float4*)&tmp[8];
            *(float4*)&sV[t][12] = *(float4*)&tmp[12];
        }
        __syncthreads();   // K/V visible

        // ---- attention: single pass, max-free softmax (scores are O(1);
        //      clamp at 60 for overflow safety, exact otherwise) ----
        float o[NDIM];
        #pragma unroll
        for (int c = 0; c < NDIM; ++c) o[c] = 0.f;
        float s0 = 0.f, s1 = 0.f, s2 = 0.f, s3 = 0.f;

        #pragma unroll 4
        for (int j = 0; j < NS; ++j) {
            const float4* kp = (const float4*)&sK[j][0];
            float4 k0 = kp[0], k1 = kp[1], k2 = kp[2], k3 = kp[3];
            float a0 = q[0]*k0.x  + q[1]*k0.y  + q[2]*k0.z  + q[3]*k0.w;
            float a1 = q[4]*k1.x  + q[5]*k1.y  + q[6]*k1.z  + q[7]*k1.w;
            float a2 = q[8]*k2.x  + q[9]*k2.y  + q[10]*k2.z + q[11]*k2.w;
            float a3 = q[12]*k3.x + q[13]*k3.y + q[14]*k3.z + q[15]*k3.w;
            float p0 = __expf(fminf(a0, 60.f));
            float p1 = __expf(fminf(a1, 60.f));
            float p2 = __expf(fminf(a2, 60.f));
            float p3 = __expf(fminf(a3, 60.f));
            s0 += p0; s1 += p1; s2 += p2; s3 += p3;
            const float4* vp = (const float4*)&sV[j][0];
            float4 v0 = vp[0], v1 = vp[1], v2 = vp[2], v3 = vp[3];
            o[0]  += p0*v0.x; o[1]  += p0*v0.y; o[2]  += p0*v0.z; o[3]  += p0*v0.w;
            o[4]  += p1*v1.x; o[5]  += p1*v1.y; o[6]  += p1*v1.z; o[7]  += p1*v1.w;
            o[8]  += p2*v2.x; o[9]  += p2*v2.y; o[10] += p2*v2.z; o[11] += p2*v2.w;
            o[12] += p3*v3.x; o[13] += p3*v3.y; o[14] += p3*v3.z; o[15] += p3*v3.w;
        }
        {
            float i0 = 1.f/s0, i1 = 1.f/s1, i2 = 1.f/s2, i3 = 1.f/s3;
            o[0]*=i0;  o[1]*=i0;  o[2]*=i0;  o[3]*=i0;
            o[4]*=i1;  o[5]*=i1;  o[6]*=i1;  o[7]*=i1;
            o[8]*=i2;  o[9]*=i2;  o[10]*=i2; o[11]*=i2;
            o[12]*=i3; o[13]*=i3; o[14]*=i3; o[15]*=i3;
        }

        // ---- output projection + residual ----
        {
            const float* ow = &sWow[li*NDIM*NDIM];
            const float* ob = &sWob[li*NDIM];
            #pragma unroll
            for (int c = 0; c < NDIM; ++c) {
                float acc = ob[c];
                #pragma unroll
                for (int k = 0; k < NDIM; ++k) acc += o[k]*ow[c*NDIM+k];
                xr[c] += acc;
            }
        }

        // ---- LN2 + MLP (hidden=4, exact gelu) + residual ----
        {
            float mu2 = 0.f;
            #pragma unroll
            for (int c = 0; c < NDIM; ++c) mu2 += xr[c];
            mu2 *= (1.f/NDIM);
            float var2 = 0.f;
            #pragma unroll
            for (int c = 0; c < NDIM; ++c) { float d = xr[c]-mu2; var2 += d*d; }
            var2 *= (1.f/NDIM);
            float rs2 = rsqrtf(var2 + LEPS);
            #pragma unroll
            for (int c = 0; c < NDIM; ++c)
                hn[c] = (xr[c]-mu2)*rs2*sLn2g[li*NDIM+c] + sLn2b[li*NDIM+c];

            const float* w1p = &sW1[li*NMLP*NDIM];
            float h1[NMLP];
            #pragma unroll
            for (int m = 0; m < NMLP; ++m) {
                float acc = sB1[li*NMLP+m];
                #pragma unroll
                for (int c = 0; c < NDIM; ++c) acc += hn[c]*w1p[m*NDIM+c];
                h1[m] = 0.5f*acc*(1.f + erff(acc*0.70710678118654752f));
            }
            const float* w2p = &sW2[li*NDIM*NMLP];
            #pragma unroll
            for (int c = 0; c < NDIM; ++c) {
                float acc = sB2[li*NDIM+c];
                #pragma unroll
                for (int m = 0; m < NMLP; ++m) acc += h1[m]*w2p[c*NMLP+m];
                xr[c] += acc;
            }
        }
    }

    // ---- head: only row 0 of each batch element matters ----
    if (t == 0) {
        float mu = 0.f;
        #pragma unroll
        for (int c = 0; c < NDIM; ++c) mu += xr[c];
        mu *= (1.f/NDIM);
        float var = 0.f;
        #pragma unroll
        for (int c = 0; c < NDIM; ++c) { float d = xr[c]-mu; var += d*d; }
        var *= (1.f/NDIM);
        float rs = rsqrtf(var + LEPS);
        float hn[NDIM];
        #pragma unroll
        for (int c = 0; c < NDIM; ++c)
            hn[c] = (xr[c]-mu)*rs*sHg[c] + sHb[c];
        #pragma unroll
        for (int oi = 0; oi < NOUT; ++oi) {
            float acc = sHbias[oi];
            #pragma unroll
            for (int c = 0; c < NDIM; ++c) acc += hn[c]*sHw[oi*NDIM+c];
            gout[b*NOUT + oi] = acc;
        }
    }
}

extern "C" void kernel_launch(void* const* d_in, const int* in_sizes, int n_in,
                              void* d_out, int out_size, void* d_ws, size_t ws_size,
                              hipStream_t stream) {
    const float* x       = (const float*)d_in[0];
    const float* ln1_g   = (const float*)d_in[1];
    const float* ln1_b   = (const float*)d_in[2];
    const float* in_w    = (const float*)d_in[3];
    const float* in_b    = (const float*)d_in[4];
    const float* out_w   = (const float*)d_in[5];
    const float* out_b   = (const float*)d_in[6];
    const float* ln2_g   = (const float*)d_in[7];
    const float* ln2_b   = (const float*)d_in[8];
    const float* w1      = (const float*)d_in[9];
    const float* b1      = (const float*)d_in[10];
    const float* w2      = (const float*)d_in[11];
    const float* b2      = (const float*)d_in[12];
    const float* head_g  = (const float*)d_in[13];
    const float* head_b  = (const float*)d_in[14];
    const float* head_w  = (const float*)d_in[15];
    const float* head_bias = (const float*)d_in[16];
    float* out = (float*)d_out;

    const int B = in_sizes[0] / (NS * NDIM);   // 256

    vit_fused<<<B, NS, 0, stream>>>(x, ln1_g, ln1_b, in_w, in_b, out_w, out_b,
                                    ln2_g, ln2_b, w1, b1, w2, b2,
                                    head_g, head_b, head_w, head_bias, out);
}

// Round 3
// 345.239 us; speedup vs baseline: 1.2903x; 1.2903x over previous
//
#include <hip/hip_runtime.h>
#include <math.h>

#define NDIM 16
#define NMLP 4
#define NL 4
#define NOUT 16
#define NS 512
#define LEPS 1e-5f

typedef __fp16 h2 __attribute__((ext_vector_type(2)));

__device__ __forceinline__ h2 pk2(float x, float y) {
    return __builtin_amdgcn_cvt_pkrtz(x, y);
}

__device__ __forceinline__ float fdot2(h2 a, h2 b, float c) {
#if __has_builtin(__builtin_amdgcn_fdot2)
    return __builtin_amdgcn_fdot2(a, b, c, false);
#else
    return (float)a.x * (float)b.x + (float)a.y * (float)b.y + c;
#endif
}

__device__ __forceinline__ float fexp2(float x) {
#if __has_builtin(__builtin_amdgcn_exp2f)
    return __builtin_amdgcn_exp2f(x);
#else
    return exp2f(x);
#endif
}

// One block per batch element; one thread per sequence row.
// x-row in registers across all layers. K (row-major) and V (transposed)
// live in LDS as f16; QK^T and PV use v_dot2_f32_f16.
__global__ __launch_bounds__(NS)
void vit_fused(const float* __restrict__ gx,
               const float* __restrict__ g_ln1g, const float* __restrict__ g_ln1b,
               const float* __restrict__ g_inw,  const float* __restrict__ g_inb,
               const float* __restrict__ g_outw, const float* __restrict__ g_outb,
               const float* __restrict__ g_ln2g, const float* __restrict__ g_ln2b,
               const float* __restrict__ g_w1,   const float* __restrict__ g_b1,
               const float* __restrict__ g_w2,   const float* __restrict__ g_b2,
               const float* __restrict__ g_hg,   const float* __restrict__ g_hb,
               const float* __restrict__ g_hw,   const float* __restrict__ g_hbias,
               float* __restrict__ gout)
{
    __shared__ __align__(16) __fp16 sKh[NS][NDIM];     // 16 KB, row-major f16
    __shared__ __align__(16) __fp16 sVT[NDIM][NS];     // 16 KB, transposed f16
    __shared__ __align__(16) float sWiw[NL*48*NDIM];   // 12 KB
    __shared__ float sWib[NL*48];
    __shared__ __align__(16) float sWow[NL*NDIM*NDIM]; // 4 KB
    __shared__ float sWob[NL*NDIM];
    __shared__ float sLn1g[NL*NDIM], sLn1b[NL*NDIM], sLn2g[NL*NDIM], sLn2b[NL*NDIM];
    __shared__ __align__(16) float sW1[NL*NMLP*NDIM];
    __shared__ float sB1[NL*NMLP];
    __shared__ __align__(16) float sW2[NL*NDIM*NMLP];
    __shared__ float sB2[NL*NDIM];
    __shared__ float sHg[NDIM], sHb[NDIM];
    __shared__ __align__(16) float sHw[NOUT*NDIM];
    __shared__ float sHbias[NOUT];

    const int t = threadIdx.x;
    const int b = blockIdx.x;

    // ---- stage all weights to LDS once ----
    for (int i = t; i < NL*48*NDIM; i += NS) sWiw[i] = g_inw[i];
    for (int i = t; i < NL*48;       i += NS) sWib[i] = g_inb[i];
    for (int i = t; i < NL*NDIM*NDIM; i += NS) sWow[i] = g_outw[i];
    if (t < NL*NDIM) {
        sWob[t]  = g_outb[t];
        sLn1g[t] = g_ln1g[t];  sLn1b[t] = g_ln1b[t];
        sLn2g[t] = g_ln2g[t];  sLn2b[t] = g_ln2b[t];
        sB2[t]   = g_b2[t];
    }
    for (int i = t; i < NL*NMLP*NDIM; i += NS) { sW1[i] = g_w1[i]; sW2[i] = g_w2[i]; }
    if (t < NL*NMLP) sB1[t] = g_b1[t];
    if (t < NDIM)  { sHg[t] = g_hg[t]; sHb[t] = g_hb[t]; }
    if (t < NOUT)    sHbias[t] = g_hbias[t];
    for (int i = t; i < NOUT*NDIM; i += NS) sHw[i] = g_hw[i];

    // ---- load my x row ----
    float xr[NDIM];
    {
        const float4* xg4 = (const float4*)(gx + ((size_t)b*NS + t)*NDIM);
        float4 a = xg4[0], b4 = xg4[1], c4 = xg4[2], d4 = xg4[3];
        xr[0]=a.x;  xr[1]=a.y;  xr[2]=a.z;  xr[3]=a.w;
        xr[4]=b4.x; xr[5]=b4.y; xr[6]=b4.z; xr[7]=b4.w;
        xr[8]=c4.x; xr[9]=c4.y; xr[10]=c4.z; xr[11]=c4.w;
        xr[12]=d4.x; xr[13]=d4.y; xr[14]=d4.z; xr[15]=d4.w;
    }

    __syncthreads();   // weights staged

    for (int li = 0; li < NL; ++li) {
        // ---- LN1 ----
        float mu = 0.f;
        #pragma unroll
        for (int c = 0; c < NDIM; ++c) mu += xr[c];
        mu *= (1.f/NDIM);
        float var = 0.f;
        #pragma unroll
        for (int c = 0; c < NDIM; ++c) { float d = xr[c]-mu; var += d*d; }
        var *= (1.f/NDIM);
        float rs = rsqrtf(var + LEPS);
        float hn[NDIM];
        #pragma unroll
        for (int c = 0; c < NDIM; ++c)
            hn[c] = (xr[c]-mu)*rs*sLn1g[li*NDIM+c] + sLn1b[li*NDIM+c];

        const float* iw = &sWiw[li*48*NDIM];
        const float* ib = &sWib[li*48];

        // q rows, pre-scaled by 1/sqrt(DH)*log2(e) = 0.5*1.442695, packed f16 pairs
        h2 qp[8];
        {
            const float C = 0.72134752044448170368f;
            float qf[NDIM];
            #pragma unroll
            for (int r = 0; r < NDIM; ++r) {
                float acc = ib[r];
                #pragma unroll
                for (int c = 0; c < NDIM; ++c) acc += hn[c]*iw[r*NDIM+c];
                qf[r] = acc*C;
            }
            #pragma unroll
            for (int i = 0; i < 8; ++i) qp[i] = pk2(qf[2*i], qf[2*i+1]);
        }

        __syncthreads();   // everyone finished reading previous layer's K/V

        // K row (packed f16, row-major) and V row (f16, transposed) -> LDS
        {
            float kr[NDIM];
            #pragma unroll
            for (int r = 0; r < NDIM; ++r) {
                float acc = ib[16+r];
                #pragma unroll
                for (int c = 0; c < NDIM; ++c) acc += hn[c]*iw[(16+r)*NDIM+c];
                kr[r] = acc;
            }
            h2 kt[8];
            #pragma unroll
            for (int i = 0; i < 8; ++i) kt[i] = pk2(kr[2*i], kr[2*i+1]);
            *(float4*)&sKh[t][0] = ((const float4*)kt)[0];
            *(float4*)&sKh[t][8] = ((const float4*)kt)[1];

            #pragma unroll
            for (int r = 0; r < NDIM; ++r) {
                float acc = ib[32+r];
                #pragma unroll
                for (int c = 0; c < NDIM; ++c) acc += hn[c]*iw[(32+r)*NDIM+c];
                sVT[r][t] = (__fp16)acc;
            }
        }
        __syncthreads();   // K/V visible

        // ---- attention: scores in log2 domain, max-free softmax ----
        float o[NDIM];
        #pragma unroll
        for (int c = 0; c < NDIM; ++c) o[c] = 0.f;
        float s[4] = {0.f, 0.f, 0.f, 0.f};
        h2 one2; one2.x = (__fp16)1.0f; one2.y = (__fp16)1.0f;

        for (int jj = 0; jj < NS; jj += 8) {
            float4 vt4[NDIM];
            #pragma unroll
            for (int c = 0; c < NDIM; ++c) vt4[c] = *(const float4*)&sVT[c][jj];

            #pragma unroll
            for (int p = 0; p < 4; ++p) {
                const int j0 = jj + 2*p;
                float e0[4], e1[4];
                {
                    float4 ka = *(const float4*)&sKh[j0][0];
                    float4 kb = *(const float4*)&sKh[j0][8];
                    const h2* kA = (const h2*)&ka;
                    const h2* kB = (const h2*)&kb;
                    float a0 = fdot2(qp[1], kA[1], fdot2(qp[0], kA[0], 0.f));
                    float a1 = fdot2(qp[3], kA[3], fdot2(qp[2], kA[2], 0.f));
                    float a2 = fdot2(qp[5], kB[1], fdot2(qp[4], kB[0], 0.f));
                    float a3 = fdot2(qp[7], kB[3], fdot2(qp[6], kB[2], 0.f));
                    e0[0] = fexp2(fminf(a0, 14.f));
                    e0[1] = fexp2(fminf(a1, 14.f));
                    e0[2] = fexp2(fminf(a2, 14.f));
                    e0[3] = fexp2(fminf(a3, 14.f));
                }
                {
                    float4 ka = *(const float4*)&sKh[j0+1][0];
                    float4 kb = *(const float4*)&sKh[j0+1][8];
                    const h2* kA = (const h2*)&ka;
                    const h2* kB = (const h2*)&kb;
                    float a0 = fdot2(qp[1], kA[1], fdot2(qp[0], kA[0], 0.f));
                    float a1 = fdot2(qp[3], kA[3], fdot2(qp[2], kA[2], 0.f));
                    float a2 = fdot2(qp[5], kB[1], fdot2(qp[4], kB[0], 0.f));
                    float a3 = fdot2(qp[7], kB[3], fdot2(qp[6], kB[2], 0.f));
                    e1[0] = fexp2(fminf(a0, 14.f));
                    e1[1] = fexp2(fminf(a1, 14.f));
                    e1[2] = fexp2(fminf(a2, 14.f));
                    e1[3] = fexp2(fminf(a3, 14.f));
                }
                h2 pk[4];
                #pragma unroll
                for (int h = 0; h < 4; ++h) pk[h] = pk2(e0[h], e1[h]);
                #pragma unroll
                for (int h = 0; h < 4; ++h) s[h] = fdot2(pk[h], one2, s[h]);
                #pragma unroll
                for (int c = 0; c < NDIM; ++c) {
                    h2 vv = ((const h2*)&vt4[c])[p];
                    o[c] = fdot2(pk[c>>2], vv, o[c]);
                }
            }
        }
        {
            float i0 = 1.f/s[0], i1 = 1.f/s[1], i2 = 1.f/s[2], i3 = 1.f/s[3];
            o[0]*=i0;  o[1]*=i0;  o[2]*=i0;  o[3]*=i0;
            o[4]*=i1;  o[5]*=i1;  o[6]*=i1;  o[7]*=i1;
            o[8]*=i2;  o[9]*=i2;  o[10]*=i2; o[11]*=i2;
            o[12]*=i3; o[13]*=i3; o[14]*=i3; o[15]*=i3;
        }

        // ---- output projection + residual ----
        {
            const float* ow = &sWow[li*NDIM*NDIM];
            const float* ob = &sWob[li*NDIM];
            #pragma unroll
            for (int c = 0; c < NDIM; ++c) {
                float acc = ob[c];
                #pragma unroll
                for (int k = 0; k < NDIM; ++k) acc += o[k]*ow[c*NDIM+k];
                xr[c] += acc;
            }
        }

        // ---- LN2 + MLP + residual ----
        {
            float mu2 = 0.f;
            #pragma unroll
            for (int c = 0; c < NDIM; ++c) mu2 += xr[c];
            mu2 *= (1.f/NDIM);
            float var2 = 0.f;
            #pragma unroll
            for (int c = 0; c < NDIM; ++c) { float d = xr[c]-mu2; var2 += d*d; }
            var2 *= (1.f/NDIM);
            float rs2 = rsqrtf(var2 + LEPS);
            float hn2[NDIM];
            #pragma unroll
            for (int c = 0; c < NDIM; ++c)
                hn2[c] = (xr[c]-mu2)*rs2*sLn2g[li*NDIM+c] + sLn2b[li*NDIM+c];

            const float* w1p = &sW1[li*NMLP*NDIM];
            float h1[NMLP];
            #pragma unroll
            for (int m = 0; m < NMLP; ++m) {
                float acc = sB1[li*NMLP+m];
                #pragma unroll
                for (int c = 0; c < NDIM; ++c) acc += hn2[c]*w1p[m*NDIM+c];
                h1[m] = 0.5f*acc*(1.f + erff(acc*0.70710678118654752f));
            }
            const float* w2p = &sW2[li*NDIM*NMLP];
            #pragma unroll
            for (int c = 0; c < NDIM; ++c) {
                float acc = sB2[li*NDIM+c];
                #pragma unroll
                for (int m = 0; m < NMLP; ++m) acc += h1[m]*w2p[c*NMLP+m];
                xr[c] += acc;
            }
        }
    }

    // ---- head: only row 0 matters ----
    if (t == 0) {
        float mu = 0.f;
        #pragma unroll
        for (int c = 0; c < NDIM; ++c) mu += xr[c];
        mu *= (1.f/NDIM);
        float var = 0.f;
        #pragma unroll
        for (int c = 0; c < NDIM; ++c) { float d = xr[c]-mu; var += d*d; }
        var *= (1.f/NDIM);
        float rs = rsqrtf(var + LEPS);
        float hn[NDIM];
        #pragma unroll
        for (int c = 0; c < NDIM; ++c)
            hn[c] = (xr[c]-mu)*rs*sHg[c] + sHb[c];
        #pragma unroll
        for (int oi = 0; oi < NOUT; ++oi) {
            float acc = sHbias[oi];
            #pragma unroll
            for (int c = 0; c < NDIM; ++c) acc += hn[c]*sHw[oi*NDIM+c];
            gout[b*NOUT + oi] = acc;
        }
    }
}

extern "C" void kernel_launch(void* const* d_in, const int* in_sizes, int n_in,
                              void* d_out, int out_size, void* d_ws, size_t ws_size,
                              hipStream_t stream) {
    const float* x       = (const float*)d_in[0];
    const float* ln1_g   = (const float*)d_in[1];
    const float* ln1_b   = (const float*)d_in[2];
    const float* in_w    = (const float*)d_in[3];
    const float* in_b    = (const float*)d_in[4];
    const float* out_w   = (const float*)d_in[5];
    const float* out_b   = (const float*)d_in[6];
    const float* ln2_g   = (const float*)d_in[7];
    const float* ln2_b   = (const float*)d_in[8];
    const float* w1      = (const float*)d_in[9];
    const float* b1      = (const float*)d_in[10];
    const float* w2      = (const float*)d_in[11];
    const float* b2      = (const float*)d_in[12];
    const float* head_g  = (const float*)d_in[13];
    const float* head_b  = (const float*)d_in[14];
    const float* head_w  = (const float*)d_in[15];
    const float* head_bias = (const float*)d_in[16];
    float* out = (float*)d_out;

    const int B = in_sizes[0] / (NS * NDIM);   // 256

    vit_fused<<<B, NS, 0, stream>>>(x, ln1_g, ln1_b, in_w, in_b, out_w, out_b,
                                    ln2_g, ln2_b, w1, b1, w2, b2,
                                    head_g, head_b, head_w, head_bias, out);
}

// Round 4
// 307.301 us; speedup vs baseline: 1.4496x; 1.1235x over previous
//
#include <hip/hip_runtime.h>
#include <math.h>

#define NDIM 16
#define NMLP 4
#define NL 4
#define NOUT 16
#define NS 512
#define NT 1024
#define LEPS 1e-5f

typedef __fp16 h2 __attribute__((ext_vector_type(2)));

__device__ __forceinline__ h2 pk2(float x, float y) {
    return __builtin_amdgcn_cvt_pkrtz(x, y);
}

__device__ __forceinline__ float fdot2(h2 a, h2 b, float c) {
#if __has_builtin(__builtin_amdgcn_fdot2)
    return __builtin_amdgcn_fdot2(a, b, c, false);
#else
    return (float)a.x * (float)b.x + (float)a.y * (float)b.y + c;
#endif
}

__device__ __forceinline__ float fexp2(float x) {
#if __has_builtin(__builtin_amdgcn_exp2f)
    return __builtin_amdgcn_exp2f(x);
#else
    return exp2f(x);
#endif
}

// 1024 threads per block: threads t and t+512 both own row t.
// Lower half handles heads 0,1 (dims 0-7); upper half heads 2,3 (dims 8-15).
// Each keeps a redundant xr copy; o halves are exchanged via LDS per layer.
__global__ __launch_bounds__(NT)
void vit_fused(const float* __restrict__ gx,
               const float* __restrict__ g_ln1g, const float* __restrict__ g_ln1b,
               const float* __restrict__ g_inw,  const float* __restrict__ g_inb,
               const float* __restrict__ g_outw, const float* __restrict__ g_outb,
               const float* __restrict__ g_ln2g, const float* __restrict__ g_ln2b,
               const float* __restrict__ g_w1,   const float* __restrict__ g_b1,
               const float* __restrict__ g_w2,   const float* __restrict__ g_b2,
               const float* __restrict__ g_hg,   const float* __restrict__ g_hb,
               const float* __restrict__ g_hw,   const float* __restrict__ g_hbias,
               float* __restrict__ gout)
{
    __shared__ __align__(16) __fp16 sKh[NS][NDIM];     // 16 KB rows of K, f16
    __shared__ __align__(16) __fp16 sVT[NDIM][NS];     // 16 KB V transposed, f16
    __shared__ __align__(16) __fp16 sOX[NS][NDIM];     // 16 KB o-exchange, f16
    __shared__ __align__(16) float sWiw[NL*48*NDIM];   // 12 KB
    __shared__ float sWib[NL*48];
    __shared__ __align__(16) float sWow[NL*NDIM*NDIM]; // 4 KB
    __shared__ float sWob[NL*NDIM];
    __shared__ float sLn1g[NL*NDIM], sLn1b[NL*NDIM], sLn2g[NL*NDIM], sLn2b[NL*NDIM];
    __shared__ __align__(16) float sW1[NL*NMLP*NDIM];
    __shared__ float sB1[NL*NMLP];
    __shared__ __align__(16) float sW2[NL*NDIM*NMLP];
    __shared__ float sB2[NL*NDIM];
    __shared__ float sHg[NDIM], sHb[NDIM];
    __shared__ __align__(16) float sHw[NOUT*NDIM];
    __shared__ float sHbias[NOUT];

    const int tid = threadIdx.x;
    const int t   = tid & (NS-1);        // sequence row
    const int hb  = (tid >> 9) << 3;     // 0 (heads 0,1) or 8 (heads 2,3)
    const int b   = blockIdx.x;

    // ---- stage all weights to LDS once ----
    for (int i = tid; i < NL*48*NDIM; i += NT) sWiw[i] = g_inw[i];
    for (int i = tid; i < NL*48;       i += NT) sWib[i] = g_inb[i];
    for (int i = tid; i < NL*NDIM*NDIM; i += NT) sWow[i] = g_outw[i];
    if (tid < NL*NDIM) {
        sWob[tid]  = g_outb[tid];
        sLn1g[tid] = g_ln1g[tid];  sLn1b[tid] = g_ln1b[tid];
        sLn2g[tid] = g_ln2g[tid];  sLn2b[tid] = g_ln2b[tid];
        sB2[tid]   = g_b2[tid];
    }
    for (int i = tid; i < NL*NMLP*NDIM; i += NT) { sW1[i] = g_w1[i]; sW2[i] = g_w2[i]; }
    if (tid < NL*NMLP) sB1[tid] = g_b1[tid];
    if (tid < NDIM)  { sHg[tid] = g_hg[tid]; sHb[tid] = g_hb[tid]; }
    if (tid < NOUT)    sHbias[tid] = g_hbias[tid];
    for (int i = tid; i < NOUT*NDIM; i += NT) sHw[i] = g_hw[i];

    // ---- load my x row (both halves load the same row; L2 broadcast) ----
    float xr[NDIM];
    {
        const float4* xg4 = (const float4*)(gx + ((size_t)b*NS + t)*NDIM);
        float4 a = xg4[0], b4 = xg4[1], c4 = xg4[2], d4 = xg4[3];
        xr[0]=a.x;  xr[1]=a.y;  xr[2]=a.z;  xr[3]=a.w;
        xr[4]=b4.x; xr[5]=b4.y; xr[6]=b4.z; xr[7]=b4.w;
        xr[8]=c4.x; xr[9]=c4.y; xr[10]=c4.z; xr[11]=c4.w;
        xr[12]=d4.x; xr[13]=d4.y; xr[14]=d4.z; xr[15]=d4.w;
    }

    __syncthreads();   // weights staged

    for (int li = 0; li < NL; ++li) {
        // ---- LN1 (redundant in both halves) ----
        float mu = 0.f;
        #pragma unroll
        for (int c = 0; c < NDIM; ++c) mu += xr[c];
        mu *= (1.f/NDIM);
        float var = 0.f;
        #pragma unroll
        for (int c = 0; c < NDIM; ++c) { float d = xr[c]-mu; var += d*d; }
        var *= (1.f/NDIM);
        float rs = rsqrtf(var + LEPS);
        float hn[NDIM];
        #pragma unroll
        for (int c = 0; c < NDIM; ++c)
            hn[c] = (xr[c]-mu)*rs*sLn1g[li*NDIM+c] + sLn1b[li*NDIM+c];

        const float* iw = &sWiw[li*48*NDIM];
        const float* ib = &sWib[li*48];

        // my 8 q dims, pre-scaled by 0.5*log2(e); my 8 k dims; my 8 v dims
        h2 qp[4];
        {
            const float C = 0.72134752044448170368f;
            float qf[8];
            #pragma unroll
            for (int r = 0; r < 8; ++r) {
                const float* wrow = &iw[(hb+r)*NDIM];
                float acc = ib[hb+r];
                #pragma unroll
                for (int c = 0; c < NDIM; ++c) acc += hn[c]*wrow[c];
                qf[r] = acc*C;
            }
            #pragma unroll
            for (int i = 0; i < 4; ++i) qp[i] = pk2(qf[2*i], qf[2*i+1]);
        }
        float kr[8], vr[8];
        #pragma unroll
        for (int r = 0; r < 8; ++r) {
            const float* wrow = &iw[(16+hb+r)*NDIM];
            float acc = ib[16+hb+r];
            #pragma unroll
            for (int c = 0; c < NDIM; ++c) acc += hn[c]*wrow[c];
            kr[r] = acc;
        }
        #pragma unroll
        for (int r = 0; r < 8; ++r) {
            const float* wrow = &iw[(32+hb+r)*NDIM];
            float acc = ib[32+hb+r];
            #pragma unroll
            for (int c = 0; c < NDIM; ++c) acc += hn[c]*wrow[c];
            vr[r] = acc;
        }

        // write my K half (packed f16, one b128) and V half (transposed)
        {
            h2 kt[4];
            #pragma unroll
            for (int i = 0; i < 4; ++i) kt[i] = pk2(kr[2*i], kr[2*i+1]);
            *(float4*)&sKh[t][hb] = *(const float4*)kt;
            #pragma unroll
            for (int r = 0; r < 8; ++r) sVT[hb+r][t] = (__fp16)vr[r];
        }
        __syncthreads();   // B1: K/V visible

        // ---- attention over my 2 heads (dims hb..hb+7) ----
        float o[8];
        #pragma unroll
        for (int c = 0; c < 8; ++c) o[c] = 0.f;
        float s0 = 0.f, s1 = 0.f;
        h2 one2; one2.x = (__fp16)1.0f; one2.y = (__fp16)1.0f;

        for (int jj = 0; jj < NS; jj += 8) {
            float4 vt4[8];
            #pragma unroll
            for (int c = 0; c < 8; ++c) vt4[c] = *(const float4*)&sVT[hb+c][jj];

            #pragma unroll
            for (int p = 0; p < 4; ++p) {
                const int j0 = jj + 2*p;
                float4 ka = *(const float4*)&sKh[j0][hb];
                const h2* kA = (const h2*)&ka;
                float a0 = fdot2(qp[1], kA[1], fdot2(qp[0], kA[0], 0.f));
                float a1 = fdot2(qp[3], kA[3], fdot2(qp[2], kA[2], 0.f));
                float4 kb = *(const float4*)&sKh[j0+1][hb];
                const h2* kB = (const h2*)&kb;
                float b0 = fdot2(qp[1], kB[1], fdot2(qp[0], kB[0], 0.f));
                float b1 = fdot2(qp[3], kB[3], fdot2(qp[2], kB[2], 0.f));
                float e00 = fexp2(a0), e01 = fexp2(a1);
                float e10 = fexp2(b0), e11 = fexp2(b1);
                h2 p0 = pk2(e00, e10);   // head lo, keys (j0, j0+1)
                h2 p1 = pk2(e01, e11);   // head hi
                s0 = fdot2(p0, one2, s0);
                s1 = fdot2(p1, one2, s1);
                #pragma unroll
                for (int c = 0; c < 8; ++c) {
                    h2 vv = ((const h2*)&vt4[c])[p];
                    o[c] = fdot2((c < 4) ? p0 : p1, vv, o[c]);
                }
            }
        }
        {
            float i0 = 1.f/s0, i1 = 1.f/s1;
            o[0]*=i0; o[1]*=i0; o[2]*=i0; o[3]*=i0;
            o[4]*=i1; o[5]*=i1; o[6]*=i1; o[7]*=i1;
        }

        // ---- exchange o halves (f16) ----
        {
            h2 oh[4];
            #pragma unroll
            for (int i = 0; i < 4; ++i) oh[i] = pk2(o[2*i], o[2*i+1]);
            *(float4*)&sOX[t][hb] = *(const float4*)oh;
        }
        __syncthreads();   // B2: all o halves written (and all j-loops done)

        float of[NDIM];
        {
            float4 lo = *(const float4*)&sOX[t][0];
            float4 hi = *(const float4*)&sOX[t][8];
            const h2* l2 = (const h2*)&lo;
            const h2* h2p = (const h2*)&hi;
            #pragma unroll
            for (int i = 0; i < 4; ++i) {
                of[2*i]   = (float)l2[i].x;  of[2*i+1]   = (float)l2[i].y;
                of[8+2*i] = (float)h2p[i].x; of[8+2*i+1] = (float)h2p[i].y;
            }
        }

        // ---- output projection + residual (redundant both halves) ----
        {
            const float* ow = &sWow[li*NDIM*NDIM];
            const float* ob = &sWob[li*NDIM];
            #pragma unroll
            for (int c = 0; c < NDIM; ++c) {
                float acc = ob[c];
                #pragma unroll
                for (int k = 0; k < NDIM; ++k) acc += of[k]*ow[c*NDIM+k];
                xr[c] += acc;
            }
        }

        // ---- LN2 + MLP + residual (redundant both halves) ----
        {
            float mu2 = 0.f;
            #pragma unroll
            for (int c = 0; c < NDIM; ++c) mu2 += xr[c];
            mu2 *= (1.f/NDIM);
            float var2 = 0.f;
            #pragma unroll
            for (int c = 0; c < NDIM; ++c) { float d = xr[c]-mu2; var2 += d*d; }
            var2 *= (1.f/NDIM);
            float rs2 = rsqrtf(var2 + LEPS);
            float hn2[NDIM];
            #pragma unroll
            for (int c = 0; c < NDIM; ++c)
                hn2[c] = (xr[c]-mu2)*rs2*sLn2g[li*NDIM+c] + sLn2b[li*NDIM+c];

            const float* w1p = &sW1[li*NMLP*NDIM];
            float h1[NMLP];
            #pragma unroll
            for (int m = 0; m < NMLP; ++m) {
                float acc = sB1[li*NMLP+m];
                #pragma unroll
                for (int c = 0; c < NDIM; ++c) acc += hn2[c]*w1p[m*NDIM+c];
                h1[m] = 0.5f*acc*(1.f + erff(acc*0.70710678118654752f));
            }
            const float* w2p = &sW2[li*NDIM*NMLP];
            #pragma unroll
            for (int c = 0; c < NDIM; ++c) {
                float acc = sB2[li*NDIM+c];
                #pragma unroll
                for (int m = 0; m < NMLP; ++m) acc += h1[m]*w2p[c*NMLP+m];
                xr[c] += acc;
            }
        }
    }

    // ---- head: only row 0, lower half ----
    if (tid == 0) {
        float mu = 0.f;
        #pragma unroll
        for (int c = 0; c < NDIM; ++c) mu += xr[c];
        mu *= (1.f/NDIM);
        float var = 0.f;
        #pragma unroll
        for (int c = 0; c < NDIM; ++c) { float d = xr[c]-mu; var += d*d; }
        var *= (1.f/NDIM);
        float rs = rsqrtf(var + LEPS);
        float hn[NDIM];
        #pragma unroll
        for (int c = 0; c < NDIM; ++c)
            hn[c] = (xr[c]-mu)*rs*sHg[c] + sHb[c];
        #pragma unroll
        for (int oi = 0; oi < NOUT; ++oi) {
            float acc = sHbias[oi];
            #pragma unroll
            for (int c = 0; c < NDIM; ++c) acc += hn[c]*sHw[oi*NDIM+c];
            gout[b*NOUT + oi] = acc;
        }
    }
}

extern "C" void kernel_launch(void* const* d_in, const int* in_sizes, int n_in,
                              void* d_out, int out_size, void* d_ws, size_t ws_size,
                              hipStream_t stream) {
    const float* x       = (const float*)d_in[0];
    const float* ln1_g   = (const float*)d_in[1];
    const float* ln1_b   = (const float*)d_in[2];
    const float* in_w    = (const float*)d_in[3];
    const float* in_b    = (const float*)d_in[4];
    const float* out_w   = (const float*)d_in[5];
    const float* out_b   = (const float*)d_in[6];
    const float* ln2_g   = (const float*)d_in[7];
    const float* ln2_b   = (const float*)d_in[8];
    const float* w1      = (const float*)d_in[9];
    const float* b1      = (const float*)d_in[10];
    const float* w2      = (const float*)d_in[11];
    const float* b2      = (const float*)d_in[12];
    const float* head_g  = (const float*)d_in[13];
    const float* head_b  = (const float*)d_in[14];
    const float* head_w  = (const float*)d_in[15];
    const float* head_bias = (const float*)d_in[16];
    float* out = (float*)d_out;

    const int B = in_sizes[0] / (NS * NDIM);   // 256

    vit_fused<<<B, NT, 0, stream>>>(x, ln1_g, ln1_b, in_w, in_b, out_w, out_b,
                                    ln2_g, ln2_b, w1, b1, w2, b2,
                                    head_g, head_b, head_w, head_bias, out);
}

// Round 6
// 183.352 us; speedup vs baseline: 2.4296x; 1.6760x over previous
//
#include <hip/hip_runtime.h>
#include <math.h>

#define NDIM 16
#define NMLP 4
#define NL 4
#define NOUT 16
#define NS 512
#define NT 1024
#define LEPS 1e-5f
#define VPAD 516

typedef __fp16 h2 __attribute__((ext_vector_type(2)));
typedef __fp16 h4 __attribute__((ext_vector_type(4)));
typedef float f32x4 __attribute__((ext_vector_type(4)));

__device__ __forceinline__ h2 pk2(float x, float y) {
    return __builtin_amdgcn_cvt_pkrtz(x, y);
}

__device__ __forceinline__ float fexp2(float x) {
#if __has_builtin(__builtin_amdgcn_exp2f)
    return __builtin_amdgcn_exp2f(x);
#else
    return exp2f(x);
#endif
}

#define MFMA16(a,b,c) __builtin_amdgcn_mfma_f32_16x16x16f16((a),(b),(c),0,0,0)

// 1024 threads/block, 1 block per batch element.
// Phase A (per-thread): LN1 + qkv halves -> Q,K (row-major f16), V^T (f16) in LDS.
// Phase B (per-wave MFMA): wave w owns q-rows 32w..32w+31 (2 16-row tiles).
//   T = mfma(K_tile, Q_masked_head)  -> scores^T per head (C-frag: qr=lane&15)
//   exp (VALU) -> pack f16 -> directly the B-frag of O^T += mfma(V^T, P^T).
// Phase C (per-thread): o-proj + residual + LN2 + MLP + residual.
__global__ __launch_bounds__(NT)
void vit_fused(const float* __restrict__ gx,
               const float* __restrict__ g_ln1g, const float* __restrict__ g_ln1b,
               const float* __restrict__ g_inw,  const float* __restrict__ g_inb,
               const float* __restrict__ g_outw, const float* __restrict__ g_outb,
               const float* __restrict__ g_ln2g, const float* __restrict__ g_ln2b,
               const float* __restrict__ g_w1,   const float* __restrict__ g_b1,
               const float* __restrict__ g_w2,   const float* __restrict__ g_b2,
               const float* __restrict__ g_hg,   const float* __restrict__ g_hb,
               const float* __restrict__ g_hw,   const float* __restrict__ g_hbias,
               float* __restrict__ gout)
{
    __shared__ __align__(16) __fp16 sKh[NS][NDIM];     // 16 KB K rows f16
    __shared__ __align__(16) __fp16 sVT[NDIM][VPAD];   // ~16.1 KB V^T f16 (padded)
    __shared__ __align__(16) __fp16 sQO[NS][NDIM];     // 16 KB Q then O, f16
    __shared__ __align__(16) float sWiw[NL*48*NDIM];   // 12 KB
    __shared__ float sWib[NL*48];
    __shared__ __align__(16) float sWow[NL*NDIM*NDIM]; // 4 KB
    __shared__ float sWob[NL*NDIM];
    __shared__ float sLn1g[NL*NDIM], sLn1b[NL*NDIM], sLn2g[NL*NDIM], sLn2b[NL*NDIM];
    __shared__ __align__(16) float sW1[NL*NMLP*NDIM];
    __shared__ float sB1[NL*NMLP];
    __shared__ __align__(16) float sW2[NL*NDIM*NMLP];
    __shared__ float sB2[NL*NDIM];
    __shared__ float sHg[NDIM], sHb[NDIM];
    __shared__ __align__(16) float sHw[NOUT*NDIM];
    __shared__ float sHbias[NOUT];

    const int tid = threadIdx.x;
    const int t   = tid & (NS-1);        // sequence row (phase A/C)
    const int hb  = (tid >> 9) << 3;     // 0 or 8: which 8 dims this thread computes
    const int b   = blockIdx.x;

    // wave geometry (phase B)
    const int w  = tid >> 6;             // 0..15
    const int l  = tid & 63;
    const int g  = l >> 4;               // 0..3 : k-group == head index it carries
    const int ql = l & 15;
    const int r0 = 32*w;                 // this wave's q-row base

    // ---- stage all weights to LDS once ----
    for (int i = tid; i < NL*48*NDIM; i += NT) sWiw[i] = g_inw[i];
    for (int i = tid; i < NL*48;       i += NT) sWib[i] = g_inb[i];
    for (int i = tid; i < NL*NDIM*NDIM; i += NT) sWow[i] = g_outw[i];
    if (tid < NL*NDIM) {
        sWob[tid]  = g_outb[tid];
        sLn1g[tid] = g_ln1g[tid];  sLn1b[tid] = g_ln1b[tid];
        sLn2g[tid] = g_ln2g[tid];  sLn2b[tid] = g_ln2b[tid];
        sB2[tid]   = g_b2[tid];
    }
    for (int i = tid; i < NL*NMLP*NDIM; i += NT) { sW1[i] = g_w1[i]; sW2[i] = g_w2[i]; }
    if (tid < NL*NMLP) sB1[tid] = g_b1[tid];
    if (tid < NDIM)  { sHg[tid] = g_hg[tid]; sHb[tid] = g_hb[tid]; }
    if (tid < NOUT)    sHbias[tid] = g_hbias[tid];
    for (int i = tid; i < NOUT*NDIM; i += NT) sHw[i] = g_hw[i];

    // ---- load my x row (both halves load the same row) ----
    float xr[NDIM];
    {
        const float4* xg4 = (const float4*)(gx + ((size_t)b*NS + t)*NDIM);
        float4 a = xg4[0], b4 = xg4[1], c4 = xg4[2], d4 = xg4[3];
        xr[0]=a.x;  xr[1]=a.y;  xr[2]=a.z;  xr[3]=a.w;
        xr[4]=b4.x; xr[5]=b4.y; xr[6]=b4.z; xr[7]=b4.w;
        xr[8]=c4.x; xr[9]=c4.y; xr[10]=c4.z; xr[11]=c4.w;
        xr[12]=d4.x; xr[13]=d4.y; xr[14]=d4.z; xr[15]=d4.w;
    }

    __syncthreads();   // weights staged

    for (int li = 0; li < NL; ++li) {
        // ================= Phase A: LN1 + qkv halves =================
        float mu = 0.f;
        #pragma unroll
        for (int c = 0; c < NDIM; ++c) mu += xr[c];
        mu *= (1.f/NDIM);
        float var = 0.f;
        #pragma unroll
        for (int c = 0; c < NDIM; ++c) { float d = xr[c]-mu; var += d*d; }
        var *= (1.f/NDIM);
        float rs = rsqrtf(var + LEPS);
        float hn[NDIM];
        #pragma unroll
        for (int c = 0; c < NDIM; ++c)
            hn[c] = (xr[c]-mu)*rs*sLn1g[li*NDIM+c] + sLn1b[li*NDIM+c];

        const float* iw = &sWiw[li*48*NDIM];
        const float* ib = &sWib[li*48];

        // my 8 q dims, scaled by 0.5*log2(e); write f16 to sQO
        {
            const float C = 0.72134752044448170368f;
            float qf[8];
            #pragma unroll
            for (int r = 0; r < 8; ++r) {
                const float* wrow = &iw[(hb+r)*NDIM];
                float acc = ib[hb+r];
                #pragma unroll
                for (int c = 0; c < NDIM; ++c) acc += hn[c]*wrow[c];
                qf[r] = acc*C;
            }
            h4 qlo = __builtin_shufflevector(pk2(qf[0],qf[1]), pk2(qf[2],qf[3]), 0,1,2,3);
            h4 qhi = __builtin_shufflevector(pk2(qf[4],qf[5]), pk2(qf[6],qf[7]), 0,1,2,3);
            *(h4*)&sQO[t][hb]   = qlo;
            *(h4*)&sQO[t][hb+4] = qhi;
        }
        // my 8 k dims -> sKh
        {
            float kr[8];
            #pragma unroll
            for (int r = 0; r < 8; ++r) {
                const float* wrow = &iw[(16+hb+r)*NDIM];
                float acc = ib[16+hb+r];
                #pragma unroll
                for (int c = 0; c < NDIM; ++c) acc += hn[c]*wrow[c];
                kr[r] = acc;
            }
            h4 klo = __builtin_shufflevector(pk2(kr[0],kr[1]), pk2(kr[2],kr[3]), 0,1,2,3);
            h4 khi = __builtin_shufflevector(pk2(kr[4],kr[5]), pk2(kr[6],kr[7]), 0,1,2,3);
            *(h4*)&sKh[t][hb]   = klo;
            *(h4*)&sKh[t][hb+4] = khi;
        }
        // my 8 v dims -> sVT (transposed)
        {
            #pragma unroll
            for (int r = 0; r < 8; ++r) {
                const float* wrow = &iw[(32+hb+r)*NDIM];
                float acc = ib[32+hb+r];
                #pragma unroll
                for (int c = 0; c < NDIM; ++c) acc += hn[c]*wrow[c];
                sVT[hb+r][t] = (__fp16)acc;
            }
        }
        __syncthreads();   // B1: Q/K/V visible

        // ================= Phase B: MFMA attention =================
        {
            h4 z4 = {};
            h4 q4a = *(const h4*)&sQO[r0 + ql][4*g];
            h4 q4b = *(const h4*)&sQO[r0 + 16 + ql][4*g];
            h4 bqa[4], bqb[4];
            #pragma unroll
            for (int h = 0; h < 4; ++h) {
                bqa[h] = (g == h) ? q4a : z4;
                bqb[h] = (g == h) ? q4b : z4;
            }
            f32x4 zc = {0.f, 0.f, 0.f, 0.f};
            f32x4 acc[2][4];
            float sp[2][4];
            #pragma unroll
            for (int qt = 0; qt < 2; ++qt)
                #pragma unroll
                for (int h = 0; h < 4; ++h) { acc[qt][h] = zc; sp[qt][h] = 0.f; }

            for (int jt = 0; jt < NS/16; ++jt) {
                h4 ak = *(const h4*)&sKh[16*jt + ql][4*g];
                h4 av = *(const h4*)&sVT[ql][16*jt + 4*g];
                #pragma unroll
                for (int h = 0; h < 4; ++h) {
                    f32x4 T = MFMA16(ak, bqa[h], zc);
                    float p0 = fexp2(T[0]), p1 = fexp2(T[1]),
                          p2 = fexp2(T[2]), p3 = fexp2(T[3]);
                    sp[0][h] += (p0+p1)+(p2+p3);
                    h4 pb = __builtin_shufflevector(pk2(p0,p1), pk2(p2,p3), 0,1,2,3);
                    acc[0][h] = MFMA16(av, pb, acc[0][h]);

                    T = MFMA16(ak, bqb[h], zc);
                    p0 = fexp2(T[0]); p1 = fexp2(T[1]);
                    p2 = fexp2(T[2]); p3 = fexp2(T[3]);
                    sp[1][h] += (p0+p1)+(p2+p3);
                    pb = __builtin_shufflevector(pk2(p0,p1), pk2(p2,p3), 0,1,2,3);
                    acc[1][h] = MFMA16(av, pb, acc[1][h]);
                }
            }

            // finish row-sums: reduce over lane groups (l^16, l^32)
            #pragma unroll
            for (int qt = 0; qt < 2; ++qt)
                #pragma unroll
                for (int h = 0; h < 4; ++h) {
                    float s = sp[qt][h];
                    s += __shfl_xor(s, 16);
                    s += __shfl_xor(s, 32);
                    sp[qt][h] = s;
                }

            // extract head g's O^T rows, normalize, store to sQO
            #pragma unroll
            for (int qt = 0; qt < 2; ++qt) {
                float sg = (g < 2) ? ((g == 0) ? sp[qt][0] : sp[qt][1])
                                   : ((g == 2) ? sp[qt][2] : sp[qt][3]);
                f32x4 C = (g < 2) ? ((g == 0) ? acc[qt][0] : acc[qt][1])
                                  : ((g == 2) ? acc[qt][2] : acc[qt][3]);
                float inv = 1.f / sg;
                h4 o4 = __builtin_shufflevector(pk2(C[0]*inv, C[1]*inv),
                                                pk2(C[2]*inv, C[3]*inv), 0,1,2,3);
                *(h4*)&sQO[r0 + 16*qt + ql][4*g] = o4;
            }
        }
        __syncthreads();   // B2: O visible

        float of[NDIM];
        {
            float4 lo = *(const float4*)&sQO[t][0];
            float4 hi = *(const float4*)&sQO[t][8];
            const h2* l2  = (const h2*)&lo;
            const h2* h2p = (const h2*)&hi;
            #pragma unroll
            for (int i = 0; i < 4; ++i) {
                of[2*i]     = (float)l2[i].x;  of[2*i+1]   = (float)l2[i].y;
                of[8+2*i]   = (float)h2p[i].x; of[8+2*i+1] = (float)h2p[i].y;
            }
        }
        __syncthreads();   // B3: safe to overwrite LDS next layer

        // ================= Phase C: proj + residual, LN2 + MLP =================
        {
            const float* ow = &sWow[li*NDIM*NDIM];
            const float* ob = &sWob[li*NDIM];
            #pragma unroll
            for (int c = 0; c < NDIM; ++c) {
                float acc = ob[c];
                #pragma unroll
                for (int k = 0; k < NDIM; ++k) acc += of[k]*ow[c*NDIM+k];
                xr[c] += acc;
            }
        }
        {
            float mu2 = 0.f;
            #pragma unroll
            for (int c = 0; c < NDIM; ++c) mu2 += xr[c];
            mu2 *= (1.f/NDIM);
            float var2 = 0.f;
            #pragma unroll
            for (int c = 0; c < NDIM; ++c) { float d = xr[c]-mu2; var2 += d*d; }
            var2 *= (1.f/NDIM);
            float rs2 = rsqrtf(var2 + LEPS);
            float hn2[NDIM];
            #pragma unroll
            for (int c = 0; c < NDIM; ++c)
                hn2[c] = (xr[c]-mu2)*rs2*sLn2g[li*NDIM+c] + sLn2b[li*NDIM+c];

            const float* w1p = &sW1[li*NMLP*NDIM];
            float h1[NMLP];
            #pragma unroll
            for (int m = 0; m < NMLP; ++m) {
                float acc = sB1[li*NMLP+m];
                #pragma unroll
                for (int c = 0; c < NDIM; ++c) acc += hn2[c]*w1p[m*NDIM+c];
                h1[m] = 0.5f*acc*(1.f + erff(acc*0.70710678118654752f));
            }
            const float* w2p = &sW2[li*NDIM*NMLP];
            #pragma unroll
            for (int c = 0; c < NDIM; ++c) {
                float acc = sB2[li*NDIM+c];
                #pragma unroll
                for (int m = 0; m < NMLP; ++m) acc += h1[m]*w2p[c*NMLP+m];
                xr[c] += acc;
            }
        }
    }

    // ---- head: only row 0 ----
    if (tid == 0) {
        float mu = 0.f;
        #pragma unroll
        for (int c = 0; c < NDIM; ++c) mu += xr[c];
        mu *= (1.f/NDIM);
        float var = 0.f;
        #pragma unroll
        for (int c = 0; c < NDIM; ++c) { float d = xr[c]-mu; var += d*d; }
        var *= (1.f/NDIM);
        float rs = rsqrtf(var + LEPS);
        float hn[NDIM];
        #pragma unroll
        for (int c = 0; c < NDIM; ++c)
            hn[c] = (xr[c]-mu)*rs*sHg[c] + sHb[c];
        #pragma unroll
        for (int oi = 0; oi < NOUT; ++oi) {
            float acc = sHbias[oi];
            #pragma unroll
            for (int c = 0; c < NDIM; ++c) acc += hn[c]*sHw[oi*NDIM+c];
            gout[b*NOUT + oi] = acc;
        }
    }
}

extern "C" void kernel_launch(void* const* d_in, const int* in_sizes, int n_in,
                              void* d_out, int out_size, void* d_ws, size_t ws_size,
                              hipStream_t stream) {
    const float* x       = (const float*)d_in[0];
    const float* ln1_g   = (const float*)d_in[1];
    const float* ln1_b   = (const float*)d_in[2];
    const float* in_w    = (const float*)d_in[3];
    const float* in_b    = (const float*)d_in[4];
    const float* out_w   = (const float*)d_in[5];
    const float* out_b   = (const float*)d_in[6];
    const float* ln2_g   = (const float*)d_in[7];
    const float* ln2_b   = (const float*)d_in[8];
    const float* w1      = (const float*)d_in[9];
    const float* b1      = (const float*)d_in[10];
    const float* w2      = (const float*)d_in[11];
    const float* b2      = (const float*)d_in[12];
    const float* head_g  = (const float*)d_in[13];
    const float* head_b  = (const float*)d_in[14];
    const float* head_w  = (const float*)d_in[15];
    const float* head_bias = (const float*)d_in[16];
    float* out = (float*)d_out;

    const int B = in_sizes[0] / (NS * NDIM);   // 256

    vit_fused<<<B, NT, 0, stream>>>(x, ln1_g, ln1_b, in_w, in_b, out_w, out_b,
                                    ln2_g, ln2_b, w1, b1, w2, b2,
                                    head_g, head_b, head_w, head_bias, out);
}

// Round 7
// 179.215 us; speedup vs baseline: 2.4857x; 1.0231x over previous
//
#include <hip/hip_runtime.h>
#include <math.h>

#define NDIM 16
#define NMLP 4
#define NL 4
#define NOUT 16
#define NS 512
#define NT 1024
#define LEPS 1e-5f
#define VPAD 516

typedef __fp16 h2 __attribute__((ext_vector_type(2)));
typedef __fp16 h4 __attribute__((ext_vector_type(4)));
typedef __fp16 h8 __attribute__((ext_vector_type(8)));
typedef float f32x4 __attribute__((ext_vector_type(4)));

__device__ __forceinline__ h2 pk2(float x, float y) {
    return __builtin_amdgcn_cvt_pkrtz(x, y);
}

__device__ __forceinline__ float fdot2(h2 a, h2 b, float c) {
#if __has_builtin(__builtin_amdgcn_fdot2)
    return __builtin_amdgcn_fdot2(a, b, c, false);
#else
    return (float)a.x * (float)b.x + (float)a.y * (float)b.y + c;
#endif
}

__device__ __forceinline__ float fexp2(float x) {
#if __has_builtin(__builtin_amdgcn_exp2f)
    return __builtin_amdgcn_exp2f(x);
#else
    return exp2f(x);
#endif
}

#define MFMA32(a,b,c) __builtin_amdgcn_mfma_f32_16x16x32_f16((a),(b),(c),0,0,0)

// 1024 threads/block, 1 block per batch element.
// Phase A (per-thread): LN1 + qkv halves -> Q,K (row-major f16), V^T (f16) in LDS.
// Phase B (per-wave MFMA, 16x16x32f16): wave w owns q-rows 32w..32w+31.
//   QK: A = K-tile (d padded 16->32 with zeros), B = per-head-masked Q.
//   PV: one MFMA contracts 32 keys (two score tiles) into O^T.
// Phase C (per-thread): o-proj + residual + LN2 + MLP + residual.
__global__ __launch_bounds__(NT, 4)
void vit_fused(const float* __restrict__ gx,
               const float* __restrict__ g_ln1g, const float* __restrict__ g_ln1b,
               const float* __restrict__ g_inw,  const float* __restrict__ g_inb,
               const float* __restrict__ g_outw, const float* __restrict__ g_outb,
               const float* __restrict__ g_ln2g, const float* __restrict__ g_ln2b,
               const float* __restrict__ g_w1,   const float* __restrict__ g_b1,
               const float* __restrict__ g_w2,   const float* __restrict__ g_b2,
               const float* __restrict__ g_hg,   const float* __restrict__ g_hb,
               const float* __restrict__ g_hw,   const float* __restrict__ g_hbias,
               float* __restrict__ gout)
{
    __shared__ __align__(16) __fp16 sKh[NS][NDIM];     // 16 KB K rows f16
    __shared__ __align__(16) __fp16 sVT[NDIM][VPAD];   // ~16.1 KB V^T f16 (padded)
    __shared__ __align__(16) __fp16 sQO[NS][NDIM];     // 16 KB Q then O, f16
    __shared__ __align__(16) float sWiw[NL*48*NDIM];   // 12 KB
    __shared__ float sWib[NL*48];
    __shared__ __align__(16) float sWow[NL*NDIM*NDIM]; // 4 KB
    __shared__ float sWob[NL*NDIM];
    __shared__ float sLn1g[NL*NDIM], sLn1b[NL*NDIM], sLn2g[NL*NDIM], sLn2b[NL*NDIM];
    __shared__ __align__(16) float sW1[NL*NMLP*NDIM];
    __shared__ float sB1[NL*NMLP];
    __shared__ __align__(16) float sW2[NL*NDIM*NMLP];
    __shared__ float sB2[NL*NDIM];
    __shared__ float sHg[NDIM], sHb[NDIM];
    __shared__ __align__(16) float sHw[NOUT*NDIM];
    __shared__ float sHbias[NOUT];

    const int tid = threadIdx.x;
    const int t   = tid & (NS-1);        // sequence row (phase A/C)
    const int hb  = (tid >> 9) << 3;     // 0 or 8: which 8 dims this thread computes
    const int b   = blockIdx.x;

    // wave geometry (phase B)
    const int w  = tid >> 6;             // 0..15
    const int l  = tid & 63;
    const int g  = l >> 4;               // 0..3 : lane group
    const int ql = l & 15;
    const int r0 = 32*w;                 // this wave's q-row base

    // ---- stage all weights to LDS once ----
    for (int i = tid; i < NL*48*NDIM; i += NT) sWiw[i] = g_inw[i];
    for (int i = tid; i < NL*48;       i += NT) sWib[i] = g_inb[i];
    for (int i = tid; i < NL*NDIM*NDIM; i += NT) sWow[i] = g_outw[i];
    if (tid < NL*NDIM) {
        sWob[tid]  = g_outb[tid];
        sLn1g[tid] = g_ln1g[tid];  sLn1b[tid] = g_ln1b[tid];
        sLn2g[tid] = g_ln2g[tid];  sLn2b[tid] = g_ln2b[tid];
        sB2[tid]   = g_b2[tid];
    }
    for (int i = tid; i < NL*NMLP*NDIM; i += NT) { sW1[i] = g_w1[i]; sW2[i] = g_w2[i]; }
    if (tid < NL*NMLP) sB1[tid] = g_b1[tid];
    if (tid < NDIM)  { sHg[tid] = g_hg[tid]; sHb[tid] = g_hb[tid]; }
    if (tid < NOUT)    sHbias[tid] = g_hbias[tid];
    for (int i = tid; i < NOUT*NDIM; i += NT) sHw[i] = g_hw[i];

    // ---- load my x row (both halves load the same row) ----
    float xr[NDIM];
    {
        const float4* xg4 = (const float4*)(gx + ((size_t)b*NS + t)*NDIM);
        float4 a = xg4[0], b4 = xg4[1], c4 = xg4[2], d4 = xg4[3];
        xr[0]=a.x;  xr[1]=a.y;  xr[2]=a.z;  xr[3]=a.w;
        xr[4]=b4.x; xr[5]=b4.y; xr[6]=b4.z; xr[7]=b4.w;
        xr[8]=c4.x; xr[9]=c4.y; xr[10]=c4.z; xr[11]=c4.w;
        xr[12]=d4.x; xr[13]=d4.y; xr[14]=d4.z; xr[15]=d4.w;
    }

    __syncthreads();   // weights staged

    for (int li = 0; li < NL; ++li) {
        // ================= Phase A: LN1 + qkv halves =================
        float mu = 0.f;
        #pragma unroll
        for (int c = 0; c < NDIM; ++c) mu += xr[c];
        mu *= (1.f/NDIM);
        float var = 0.f;
        #pragma unroll
        for (int c = 0; c < NDIM; ++c) { float d = xr[c]-mu; var += d*d; }
        var *= (1.f/NDIM);
        float rs = rsqrtf(var + LEPS);
        float hn[NDIM];
        #pragma unroll
        for (int c = 0; c < NDIM; ++c)
            hn[c] = (xr[c]-mu)*rs*sLn1g[li*NDIM+c] + sLn1b[li*NDIM+c];

        const float* iw = &sWiw[li*48*NDIM];
        const float* ib = &sWib[li*48];

        // my 8 q dims, scaled by 0.5*log2(e); write f16 to sQO
        {
            const float C = 0.72134752044448170368f;
            float qf[8];
            #pragma unroll
            for (int r = 0; r < 8; ++r) {
                const float* wrow = &iw[(hb+r)*NDIM];
                float acc = ib[hb+r];
                #pragma unroll
                for (int c = 0; c < NDIM; ++c) acc += hn[c]*wrow[c];
                qf[r] = acc*C;
            }
            h4 qlo = __builtin_shufflevector(pk2(qf[0],qf[1]), pk2(qf[2],qf[3]), 0,1,2,3);
            h4 qhi = __builtin_shufflevector(pk2(qf[4],qf[5]), pk2(qf[6],qf[7]), 0,1,2,3);
            *(h4*)&sQO[t][hb]   = qlo;
            *(h4*)&sQO[t][hb+4] = qhi;
        }
        // my 8 k dims -> sKh
        {
            float kr[8];
            #pragma unroll
            for (int r = 0; r < 8; ++r) {
                const float* wrow = &iw[(16+hb+r)*NDIM];
                float acc = ib[16+hb+r];
                #pragma unroll
                for (int c = 0; c < NDIM; ++c) acc += hn[c]*wrow[c];
                kr[r] = acc;
            }
            h4 klo = __builtin_shufflevector(pk2(kr[0],kr[1]), pk2(kr[2],kr[3]), 0,1,2,3);
            h4 khi = __builtin_shufflevector(pk2(kr[4],kr[5]), pk2(kr[6],kr[7]), 0,1,2,3);
            *(h4*)&sKh[t][hb]   = klo;
            *(h4*)&sKh[t][hb+4] = khi;
        }
        // my 8 v dims -> sVT (transposed)
        {
            #pragma unroll
            for (int r = 0; r < 8; ++r) {
                const float* wrow = &iw[(32+hb+r)*NDIM];
                float acc = ib[32+hb+r];
                #pragma unroll
                for (int c = 0; c < NDIM; ++c) acc += hn[c]*wrow[c];
                sVT[hb+r][t] = (__fp16)acc;
            }
        }
        __syncthreads();   // B1: Q/K/V visible

        // ================= Phase B: MFMA attention (16x16x32) =================
        {
            h4 z4 = {};
            h8 z8 = {};
            h4 q4a = *(const h4*)&sQO[r0 + ql][4*g];
            h4 q4b = *(const h4*)&sQO[r0 + 16 + ql][4*g];
            h8 q8a = __builtin_shufflevector(q4a, z4, 0,1,2,3,4,5,6,7);
            h8 q8b = __builtin_shufflevector(q4b, z4, 0,1,2,3,4,5,6,7);
            h8 bqa[4], bqb[4];
            #pragma unroll
            for (int h = 0; h < 4; ++h) {
                bqa[h] = (g == h) ? q8a : z8;
                bqb[h] = (g == h) ? q8b : z8;
            }
            f32x4 zc = {0.f, 0.f, 0.f, 0.f};
            f32x4 acc[2][4];
            float sp[2][4];
            #pragma unroll
            for (int qt = 0; qt < 2; ++qt)
                #pragma unroll
                for (int h = 0; h < 4; ++h) { acc[qt][h] = zc; sp[qt][h] = 0.f; }
            h2 one2; one2.x = (__fp16)1.0f; one2.y = (__fp16)1.0f;

            for (int jj = 0; jj < NS; jj += 32) {
                // K fragments for the two 16-key tiles (d padded 16->32)
                h4 ak0 = *(const h4*)&sKh[jj + ql][4*g];
                h4 ak1 = *(const h4*)&sKh[jj + 16 + ql][4*g];
                h8 a0 = __builtin_shufflevector(ak0, z4, 0,1,2,3,4,5,6,7);
                h8 a1 = __builtin_shufflevector(ak1, z4, 0,1,2,3,4,5,6,7);
                // V^T fragment covering both tiles (elems 0-3: tile0, 4-7: tile1)
                h4 av0 = *(const h4*)&sVT[ql][jj + 4*g];
                h4 av1 = *(const h4*)&sVT[ql][jj + 16 + 4*g];
                h8 av  = __builtin_shufflevector(av0, av1, 0,1,2,3,4,5,6,7);

                #pragma unroll
                for (int h = 0; h < 4; ++h) {
                    // ---- qt 0 ----
                    {
                        f32x4 T0 = MFMA32(a0, bqa[h], zc);
                        f32x4 T1 = MFMA32(a1, bqa[h], zc);
                        h2 p0 = pk2(fexp2(T0[0]), fexp2(T0[1]));
                        h2 p1 = pk2(fexp2(T0[2]), fexp2(T0[3]));
                        h2 p2 = pk2(fexp2(T1[0]), fexp2(T1[1]));
                        h2 p3 = pk2(fexp2(T1[2]), fexp2(T1[3]));
                        sp[0][h] = fdot2(p0, one2,
                                   fdot2(p1, one2,
                                   fdot2(p2, one2,
                                   fdot2(p3, one2, sp[0][h]))));
                        h8 pb = __builtin_shufflevector(
                                    __builtin_shufflevector(p0, p1, 0,1,2,3),
                                    __builtin_shufflevector(p2, p3, 0,1,2,3),
                                    0,1,2,3,4,5,6,7);
                        acc[0][h] = MFMA32(av, pb, acc[0][h]);
                    }
                    // ---- qt 1 ----
                    {
                        f32x4 T0 = MFMA32(a0, bqb[h], zc);
                        f32x4 T1 = MFMA32(a1, bqb[h], zc);
                        h2 p0 = pk2(fexp2(T0[0]), fexp2(T0[1]));
                        h2 p1 = pk2(fexp2(T0[2]), fexp2(T0[3]));
                        h2 p2 = pk2(fexp2(T1[0]), fexp2(T1[1]));
                        h2 p3 = pk2(fexp2(T1[2]), fexp2(T1[3]));
                        sp[1][h] = fdot2(p0, one2,
                                   fdot2(p1, one2,
                                   fdot2(p2, one2,
                                   fdot2(p3, one2, sp[1][h]))));
                        h8 pb = __builtin_shufflevector(
                                    __builtin_shufflevector(p0, p1, 0,1,2,3),
                                    __builtin_shufflevector(p2, p3, 0,1,2,3),
                                    0,1,2,3,4,5,6,7);
                        acc[1][h] = MFMA32(av, pb, acc[1][h]);
                    }
                }
            }

            // finish row-sums: reduce over lane groups (l^16, l^32)
            #pragma unroll
            for (int qt = 0; qt < 2; ++qt)
                #pragma unroll
                for (int h = 0; h < 4; ++h) {
                    float s = sp[qt][h];
                    s += __shfl_xor(s, 16);
                    s += __shfl_xor(s, 32);
                    sp[qt][h] = s;
                }

            // extract head g's O^T rows, normalize, store to sQO
            #pragma unroll
            for (int qt = 0; qt < 2; ++qt) {
                float sg = (g < 2) ? ((g == 0) ? sp[qt][0] : sp[qt][1])
                                   : ((g == 2) ? sp[qt][2] : sp[qt][3]);
                f32x4 C = (g < 2) ? ((g == 0) ? acc[qt][0] : acc[qt][1])
                                  : ((g == 2) ? acc[qt][2] : acc[qt][3]);
                float inv = 1.f / sg;
                h4 o4 = __builtin_shufflevector(pk2(C[0]*inv, C[1]*inv),
                                                pk2(C[2]*inv, C[3]*inv), 0,1,2,3);
                *(h4*)&sQO[r0 + 16*qt + ql][4*g] = o4;
            }
        }
        __syncthreads();   // B2: O visible

        float of[NDIM];
        {
            float4 lo = *(const float4*)&sQO[t][0];
            float4 hi = *(const float4*)&sQO[t][8];
            const h2* l2  = (const h2*)&lo;
            const h2* h2p = (const h2*)&hi;
            #pragma unroll
            for (int i = 0; i < 4; ++i) {
                of[2*i]     = (float)l2[i].x;  of[2*i+1]   = (float)l2[i].y;
                of[8+2*i]   = (float)h2p[i].x; of[8+2*i+1] = (float)h2p[i].y;
            }
        }
        __syncthreads();   // B3: safe to overwrite LDS next layer

        // ================= Phase C: proj + residual, LN2 + MLP =================
        {
            const float* ow = &sWow[li*NDIM*NDIM];
            const float* ob = &sWob[li*NDIM];
            #pragma unroll
            for (int c = 0; c < NDIM; ++c) {
                float acc = ob[c];
                #pragma unroll
                for (int k = 0; k < NDIM; ++k) acc += of[k]*ow[c*NDIM+k];
                xr[c] += acc;
            }
        }
        {
            float mu2 = 0.f;
            #pragma unroll
            for (int c = 0; c < NDIM; ++c) mu2 += xr[c];
            mu2 *= (1.f/NDIM);
            float var2 = 0.f;
            #pragma unroll
            for (int c = 0; c < NDIM; ++c) { float d = xr[c]-mu2; var2 += d*d; }
            var2 *= (1.f/NDIM);
            float rs2 = rsqrtf(var2 + LEPS);
            float hn2[NDIM];
            #pragma unroll
            for (int c = 0; c < NDIM; ++c)
                hn2[c] = (xr[c]-mu2)*rs2*sLn2g[li*NDIM+c] + sLn2b[li*NDIM+c];

            const float* w1p = &sW1[li*NMLP*NDIM];
            float h1[NMLP];
            #pragma unroll
            for (int m = 0; m < NMLP; ++m) {
                float acc = sB1[li*NMLP+m];
                #pragma unroll
                for (int c = 0; c < NDIM; ++c) acc += hn2[c]*w1p[m*NDIM+c];
                h1[m] = 0.5f*acc*(1.f + erff(acc*0.70710678118654752f));
            }
            const float* w2p = &sW2[li*NDIM*NMLP];
            #pragma unroll
            for (int c = 0; c < NDIM; ++c) {
                float acc = sB2[li*NDIM+c];
                #pragma unroll
                for (int m = 0; m < NMLP; ++m) acc += h1[m]*w2p[c*NMLP+m];
                xr[c] += acc;
            }
        }
    }

    // ---- head: only row 0 ----
    if (tid == 0) {
        float mu = 0.f;
        #pragma unroll
        for (int c = 0; c < NDIM; ++c) mu += xr[c];
        mu *= (1.f/NDIM);
        float var = 0.f;
        #pragma unroll
        for (int c = 0; c < NDIM; ++c) { float d = xr[c]-mu; var += d*d; }
        var *= (1.f/NDIM);
        float rs = rsqrtf(var + LEPS);
        float hn[NDIM];
        #pragma unroll
        for (int c = 0; c < NDIM; ++c)
            hn[c] = (xr[c]-mu)*rs*sHg[c] + sHb[c];
        #pragma unroll
        for (int oi = 0; oi < NOUT; ++oi) {
            float acc = sHbias[oi];
            #pragma unroll
            for (int c = 0; c < NDIM; ++c) acc += hn[c]*sHw[oi*NDIM+c];
            gout[b*NOUT + oi] = acc;
        }
    }
}

extern "C" void kernel_launch(void* const* d_in, const int* in_sizes, int n_in,
                              void* d_out, int out_size, void* d_ws, size_t ws_size,
                              hipStream_t stream) {
    const float* x       = (const float*)d_in[0];
    const float* ln1_g   = (const float*)d_in[1];
    const float* ln1_b   = (const float*)d_in[2];
    const float* in_w    = (const float*)d_in[3];
    const float* in_b    = (const float*)d_in[4];
    const float* out_w   = (const float*)d_in[5];
    const float* out_b   = (const float*)d_in[6];
    const float* ln2_g   = (const float*)d_in[7];
    const float* ln2_b   = (const float*)d_in[8];
    const float* w1      = (const float*)d_in[9];
    const float* b1      = (const float*)d_in[10];
    const float* w2      = (const float*)d_in[11];
    const float* b2      = (const float*)d_in[12];
    const float* head_g  = (const float*)d_in[13];
    const float* head_b  = (const float*)d_in[14];
    const float* head_w  = (const float*)d_in[15];
    const float* head_bias = (const float*)d_in[16];
    float* out = (float*)d_out;

    const int B = in_sizes[0] / (NS * NDIM);   // 256

    vit_fused<<<B, NT, 0, stream>>>(x, ln1_g, ln1_b, in_w, in_b, out_w, out_b,
                                    ln2_g, ln2_b, w1, b1, w2, b2,
                                    head_g, head_b, head_w, head_bias, out);
}